// Round 4
// baseline (400.187 us; speedup 1.0000x reference)
//
#include <hip/hip_runtime.h>

#define B_ 4
#define LQ_ 2048
#define LK_ 2048
#define E_ 768
#define H_ 12
#define D_ 64
#define SCALE_ 0.03125f
// SCALE * log2(e) folded into Q projection so attention uses bare exp2
#define QSCALE_ 0.04508422f

using short8 = __attribute__((ext_vector_type(8))) short;
using f32x4  = __attribute__((ext_vector_type(4))) float;
using f32x16 = __attribute__((ext_vector_type(16))) float;

__device__ inline unsigned short f2bf(float f) {
    union { float f; unsigned u; } v; v.f = f;
    unsigned r = (v.u + 0x7FFFu + ((v.u >> 16) & 1u)) >> 16;
    return (unsigned short)r;
}

// pack two fp32 -> two bf16 in one u32 (round-half-up; P is softmax weight, 2% tol)
__device__ inline unsigned pkbf(float a, float b) {
    union { float f; unsigned u; } x, y; x.f = a; y.f = b;
    return ((x.u + 0x8000u) >> 16) | ((y.u + 0x8000u) & 0xffff0000u);
}

// async global->LDS, 16B per lane; LDS dest = uniform base + lane*16
__device__ inline void gll16(const void* g, void* l) {
    __builtin_amdgcn_global_load_lds(
        (const __attribute__((address_space(1))) unsigned int*)g,
        (__attribute__((address_space(3))) unsigned int*)l, 16, 0, 0);
}

// ---------------- LayerNorm: one wave per row of 768, fp32 -> bf16 ----------------
__global__ __launch_bounds__(256) void ln_kernel(
    const float* __restrict__ x, const float* __restrict__ g,
    const float* __restrict__ be, unsigned short* __restrict__ y, int rows)
{
    int wave = threadIdx.x >> 6, lane = threadIdx.x & 63;
    int row = blockIdx.x * 4 + wave;
    if (row >= rows) return;
    const float* xr = x + (size_t)row * E_;
    float4 v[3];
    float s = 0.f;
#pragma unroll
    for (int i = 0; i < 3; i++) {
        v[i] = *(const float4*)(xr + i * 256 + lane * 4);
        s += v[i].x + v[i].y + v[i].z + v[i].w;
    }
#pragma unroll
    for (int off = 32; off >= 1; off >>= 1) s += __shfl_xor(s, off);
    float mu = s * (1.0f / E_);
    float q = 0.f;
#pragma unroll
    for (int i = 0; i < 3; i++) {
        float dx = v[i].x - mu, dy = v[i].y - mu, dz = v[i].z - mu, dw = v[i].w - mu;
        q += dx * dx + dy * dy + dz * dz + dw * dw;
    }
#pragma unroll
    for (int off = 32; off >= 1; off >>= 1) q += __shfl_xor(q, off);
    float rstd = rsqrtf(q * (1.0f / E_) + 1e-5f);
    unsigned short* yr = y + (size_t)row * E_;
#pragma unroll
    for (int i = 0; i < 3; i++) {
        int c = i * 256 + lane * 4;
        float4 gv = *(const float4*)(g + c);
        float4 bv = *(const float4*)(be + c);
        ushort4 o;
        o.x = f2bf((v[i].x - mu) * rstd * gv.x + bv.x);
        o.y = f2bf((v[i].y - mu) * rstd * gv.y + bv.y);
        o.z = f2bf((v[i].z - mu) * rstd * gv.z + bv.z);
        o.w = f2bf((v[i].w - mu) * rstd * gv.w + bv.w);
        *(ushort4*)(yr + c) = o;
    }
}

// ---------------- transpose + cast: in f32 [R][C] -> out bf16 [C][R] ----------------
__global__ __launch_bounds__(256) void transpose_cast(
    const float* __restrict__ in, unsigned short* __restrict__ out, int R, int C)
{
    __shared__ float tile[32][33];
    int tx = threadIdx.x & 31, ty = threadIdx.x >> 5;
    int c0 = blockIdx.x * 32, r0 = blockIdx.y * 32;
#pragma unroll
    for (int i = 0; i < 32; i += 8)
        tile[ty + i][tx] = in[(size_t)(r0 + ty + i) * C + c0 + tx];
    __syncthreads();
#pragma unroll
    for (int i = 0; i < 32; i += 8)
        out[(size_t)(c0 + ty + i) * R + r0 + tx] = f2bf(tile[tx][ty + i]);
}

// ---------------- V transpose: Vb[bh][key][d] -> Vt[bh][d][key], bf16 ----------------
__global__ __launch_bounds__(256) void vtrans_kernel(
    const unsigned short* __restrict__ Vb, unsigned short* __restrict__ Vt)
{
    __shared__ unsigned short tile[64][72];
    int tid = threadIdx.x;
    int k0 = blockIdx.x * 64;
    size_t head = (size_t)blockIdx.y * LK_ * D_;
#pragma unroll
    for (int i = 0; i < 2; i++) {
        int row = (tid >> 3) + i * 32;
        int col = (tid & 7) * 8;
        *(short8*)(&tile[row][col]) = *(const short8*)(Vb + head + (size_t)(k0 + row) * D_ + col);
    }
    __syncthreads();
#pragma unroll
    for (int i = 0; i < 2; i++) {
        int d  = (tid >> 3) + i * 32;
        int kc = (tid & 7) * 8;
        short8 v;
#pragma unroll
        for (int j = 0; j < 8; j++) v[j] = (short)tile[kc + j][d];
        *(short8*)(Vt + head + (size_t)d * LK_ + k0 + kc) = v;
    }
}

// ---------------- GEMM: C[M][N] = A[M][K] * Bt[N][K]^T, bf16, global_load_lds staging
#define BM 128
#define BN 128
#define BK 64
__global__ __launch_bounds__(256) void gemm_kernel(
    const unsigned short* __restrict__ A, const unsigned short* __restrict__ Bt,
    int M, int N, int K, int mode,
    unsigned short* __restrict__ outQ, const float* __restrict__ freqs,
    unsigned short* __restrict__ outK, unsigned short* __restrict__ outV,
    float* __restrict__ outF, const float* __restrict__ bo, const float* __restrict__ gain)
{
    __shared__ unsigned short Asm[BM][BK];
    __shared__ unsigned short Bsm[BN][BK];
    int tid = threadIdx.x;
    int wave = tid >> 6, lane = tid & 63;
    int quad = lane >> 4, l16 = lane & 15;
    int waveM = (wave >> 1) * 64, waveN = (wave & 1) * 64;
    int bn = blockIdx.x * BN, bm = blockIdx.y * BM;
    int ro = lane >> 3, co = (lane & 7) * 8;

    f32x4 acc[4][4] = {};

    for (int k0 = 0; k0 < K; k0 += BK) {
        const unsigned short* Ag = A + (size_t)(bm + wave * 32 + ro) * K + k0 + co;
        const unsigned short* Bg = Bt + (size_t)(bn + wave * 32 + ro) * K + k0 + co;
#pragma unroll
        for (int i = 0; i < 4; i++) {
            gll16(Ag + (size_t)(i * 8) * K, &Asm[wave * 32 + i * 8][0]);
            gll16(Bg + (size_t)(i * 8) * K, &Bsm[wave * 32 + i * 8][0]);
        }
        __syncthreads();
#pragma unroll
        for (int kk = 0; kk < BK; kk += 32) {
            short8 fa[4], fb[4];
#pragma unroll
            for (int t = 0; t < 4; t++) {
                fa[t] = *(const short8*)(&Asm[waveM + t * 16 + l16][kk + quad * 8]);
                fb[t] = *(const short8*)(&Bsm[waveN + t * 16 + l16][kk + quad * 8]);
            }
#pragma unroll
            for (int mt = 0; mt < 4; mt++)
#pragma unroll
                for (int nt = 0; nt < 4; nt++)
                    acc[mt][nt] = __builtin_amdgcn_mfma_f32_16x16x32_bf16(fa[mt], fb[nt], acc[mt][nt], 0, 0, 0);
        }
        __syncthreads();
    }

    float gg = (mode == 2) ? gain[0] : 0.f;
#pragma unroll
    for (int mt = 0; mt < 4; mt++) {
#pragma unroll
        for (int nt = 0; nt < 4; nt++) {
#pragma unroll
            for (int r = 0; r < 4; r++) {
                int m = bm + waveM + mt * 16 + quad * 4 + r;
                int n = bn + waveN + nt * 16 + l16;
                float v = acc[mt][nt][r];
                if (mode == 2) {
                    outF[(size_t)m * E_ + n] = gg * (v + bo[n]);
                } else {
                    int l = m & (LQ_ - 1), bb = m >> 11;
                    float partner = __shfl_xor(v, 1);
                    if (mode == 1 && n >= E_) {
                        int nn = n - E_;
                        int h = nn >> 6, dd = nn & 63;
                        outV[(((size_t)bb * H_ + h) * LK_ + l) * D_ + dd] = f2bf(v);
                    } else {
                        int h = n >> 6, dd = n & 63;
                        const float* f = freqs + ((size_t)l * 32 + (dd >> 1)) * 2;
                        float f0 = f[0], f1 = f[1];
                        float o = ((dd & 1) == 0) ? (v * f0 - partner * f1)
                                                  : (partner * f1 + v * f0);
                        if (mode == 0) o *= QSCALE_;
                        unsigned short* dst = (mode == 0) ? outQ : outK;
                        dst[(((size_t)bb * H_ + h) * LQ_ + l) * D_ + dd] = f2bf(o);
                    }
                }
            }
        }
    }
}

// ---------------- flash attention: 32x32 MFMA, register P-transform, dbuf gll ------
// Q[B,H,LQ,64] (pre-scaled bf16), K[B,H,LK,64], Vt[B,H,64,LK] -> O[B*LQ][768] bf16
__global__ __launch_bounds__(256) void attn_kernel(
    const unsigned short* __restrict__ Qg, const unsigned short* __restrict__ Kg,
    const unsigned short* __restrict__ Vt, unsigned short* __restrict__ O)
{
    __shared__ unsigned short Ksm[2][64][64];   // [buf][key][d]
    __shared__ unsigned short Vsm[2][64][64];   // [buf][d][key]

    int tid = threadIdx.x;
    int wave = tid >> 6, lane = tid & 63;
    int l32 = lane & 31, hi = lane >> 5;
    int bh = blockIdx.y;
    int b = bh / H_, h = bh % H_;
    int qbase = blockIdx.x * 128 + wave * 32;

    const size_t head = (size_t)bh * LK_ * D_;
    const unsigned short* Qh = Qg + head;
    const unsigned short* Kh = Kg + head;
    const unsigned short* Vh = Vt + head;   // [d][key]

    // Q fragments: B-operand [k=d][n=q]: lane(n=l32,hi): d = dc*16 + hi*8 + j
    short8 qf[4];
#pragma unroll
    for (int dc = 0; dc < 4; dc++)
        qf[dc] = *(const short8*)(Qh + (size_t)(qbase + l32) * D_ + dc * 16 + hi * 8);

    f32x16 oacc[2] = {};
    float lsum = 0.f;

    int ro = lane >> 3, co = (lane & 7) * 8;   // gll lane mapping: 8 rows x 128B

    // stage tile 0 into buf 0
    {
        const unsigned short* Kp = Kh + (size_t)(wave * 16 + ro) * D_ + co;
        const unsigned short* Vp = Vh + (size_t)(wave * 16 + ro) * LK_ + co;
        gll16(Kp,            &Ksm[0][wave * 16][0]);
        gll16(Kp + 8 * D_,   &Ksm[0][wave * 16 + 8][0]);
        gll16(Vp,            &Vsm[0][wave * 16][0]);
        gll16(Vp + 8 * LK_,  &Vsm[0][wave * 16 + 8][0]);
    }
    asm volatile("s_waitcnt vmcnt(0)" ::: "memory");

    int buf = 0;
    for (int kt = 0; kt < LK_; kt += 64, buf ^= 1) {
        if (kt + 64 < LK_) {
            // prefetch next tile into other buffer; stays in flight across barrier.
            // Safe vs WAR: the end-of-body barrier below guarantees every wave has
            // finished computing on buf^1 (previous iteration) before these writes.
            const unsigned short* Kp = Kh + (size_t)(kt + 64 + wave * 16 + ro) * D_ + co;
            const unsigned short* Vp = Vh + (size_t)(wave * 16 + ro) * LK_ + kt + 64 + co;
            gll16(Kp,           &Ksm[buf ^ 1][wave * 16][0]);
            gll16(Kp + 8 * D_,  &Ksm[buf ^ 1][wave * 16 + 8][0]);
            gll16(Vp,           &Vsm[buf ^ 1][wave * 16][0]);
            gll16(Vp + 8 * LK_, &Vsm[buf ^ 1][wave * 16 + 8][0]);
            asm volatile("s_waitcnt vmcnt(4)\ns_barrier" ::: "memory");
        } else {
            asm volatile("s_waitcnt vmcnt(0)\ns_barrier" ::: "memory");
        }

#pragma unroll
        for (int half = 0; half < 2; half++) {
            // S^T[key][q]: A = K rows (M=key), B = Q (N=q), k-dim = d
            f32x16 st = {};
#pragma unroll
            for (int dc = 0; dc < 4; dc++) {
                short8 kfr = *(const short8*)(&Ksm[buf][half * 32 + l32][dc * 16 + hi * 8]);
                st = __builtin_amdgcn_mfma_f32_32x32x16_bf16(kfr, qf[dc], st, 0, 0, 0);
            }
            // exp2 + pack pairs (keys consecutive within reg pairs)
            unsigned pks[8];
#pragma unroll
            for (int t = 0; t < 8; t++) {
                float p0 = __builtin_amdgcn_exp2f(st[2 * t]);
                float p1 = __builtin_amdgcn_exp2f(st[2 * t + 1]);
                lsum += p0 + p1;
                pks[t] = pkbf(p0, p1);
            }
            unsigned y[8];
#pragma unroll
            for (int t = 0; t < 8; t++) y[t] = (unsigned)__shfl_xor((int)pks[t], 32);

            // PV: A = P[q][key] assembled in-register, B = Vt[d][key]
#pragma unroll
            for (int kk = 0; kk < 2; kk++) {
                union { unsigned u[4]; short8 s; } pf;
#pragma unroll
                for (int g = 0; g < 4; g++) {
                    int t0 = kk * 4 + (g & 1);
                    unsigned own = hi ? pks[t0 + 2] : pks[t0];
                    unsigned oth = hi ? y[t0 + 2]   : y[t0];
                    pf.u[g] = ((g >> 1) == hi) ? own : oth;
                }
#pragma unroll
                for (int dt = 0; dt < 2; dt++) {
                    short8 vfr = *(const short8*)(&Vsm[buf][dt * 32 + l32][(half * 2 + kk) * 16 + hi * 8]);
                    oacc[dt] = __builtin_amdgcn_mfma_f32_32x32x16_bf16(pf.s, vfr, oacc[dt], 0, 0, 0);
                }
            }
        }
        // WAR fence: all waves must finish reading buf before anyone prefetches
        // into it next iteration. Plain barrier — NO vmcnt drain, prefetch stays
        // in flight. lgkmcnt(0) is free here (all ds_reads already consumed).
        asm volatile("s_waitcnt lgkmcnt(0)\ns_barrier" ::: "memory");
    }

    // epilogue: total row sums, normalize, store
    lsum += __shfl_xor(lsum, 32);          // lane(q,hi) + lane(q,hi^1): total for q=l32
    float inv = 1.f / lsum;
#pragma unroll
    for (int reg = 0; reg < 16; reg++) {
        int ql = (reg & 3) + 8 * (reg >> 2) + 4 * hi;   // wave-local q row of this reg
        float iq = __shfl(inv, ql);                      // lanes 0..31 hold q=lane
        int q = qbase + ql;
        size_t base = ((size_t)b * LQ_ + q) * E_ + h * D_;
#pragma unroll
        for (int dt = 0; dt < 2; dt++)
            O[base + dt * 32 + l32] = f2bf(oacc[dt][reg] * iq);
    }
}

extern "C" void kernel_launch(void* const* d_in, const int* in_sizes, int n_in,
                              void* d_out, int out_size, void* d_ws, size_t ws_size,
                              hipStream_t stream)
{
    const float* x_q     = (const float*)d_in[0];
    const float* x_kv    = (const float*)d_in[1];
    const float* freqs_q = (const float*)d_in[2];
    const float* freqs_k = (const float*)d_in[3];
    const float* Wq      = (const float*)d_in[4];
    const float* Wkv     = (const float*)d_in[5];
    const float* Wo      = (const float*)d_in[6];
    const float* bo      = (const float*)d_in[7];
    const float* ln_q_g  = (const float*)d_in[8];
    const float* ln_q_b  = (const float*)d_in[9];
    const float* ln_kv_g = (const float*)d_in[10];
    const float* ln_kv_b = (const float*)d_in[11];
    const float* gain    = (const float*)d_in[12];
    float* out = (float*)d_out;

    unsigned short* ws = (unsigned short*)d_ws;
    const size_t SZ = (size_t)B_ * LQ_ * E_;  // 6291456
    unsigned short* xq_ln  = ws;
    unsigned short* xkv_ln = xq_ln + SZ;
    unsigned short* Qb     = xkv_ln + SZ;
    unsigned short* Kb     = Qb + SZ;
    unsigned short* Vb     = Kb + SZ;
    unsigned short* Ob     = xq_ln;            // reuse (dead after Q GEMM)
    unsigned short* Vt     = xkv_ln;           // reuse (dead after KV GEMM)
    unsigned short* WqT    = Vb + SZ;
    unsigned short* WkvT   = WqT + E_ * E_;
    unsigned short* WoT    = WkvT + 2 * E_ * E_;

    ln_kernel<<<2048, 256, 0, stream>>>(x_q,  ln_q_g,  ln_q_b,  xq_ln,  B_ * LQ_);
    ln_kernel<<<2048, 256, 0, stream>>>(x_kv, ln_kv_g, ln_kv_b, xkv_ln, B_ * LK_);
    transpose_cast<<<dim3(24, 24), 256, 0, stream>>>(Wq,  WqT,  E_, E_);
    transpose_cast<<<dim3(48, 24), 256, 0, stream>>>(Wkv, WkvT, E_, 2 * E_);
    transpose_cast<<<dim3(24, 24), 256, 0, stream>>>(Wo,  WoT,  E_, E_);
    gemm_kernel<<<dim3(6, 64), 256, 0, stream>>>(xq_ln, WqT, B_ * LQ_, E_, E_, 0,
                                                 Qb, freqs_q, nullptr, nullptr, nullptr, nullptr, nullptr);
    gemm_kernel<<<dim3(12, 64), 256, 0, stream>>>(xkv_ln, WkvT, B_ * LK_, 2 * E_, E_, 1,
                                                  nullptr, freqs_k, Kb, Vb, nullptr, nullptr, nullptr);
    vtrans_kernel<<<dim3(32, 48), 256, 0, stream>>>(Vb, Vt);
    attn_kernel<<<dim3(16, 48), 256, 0, stream>>>(Qb, Kb, Vt, Ob);
    gemm_kernel<<<dim3(6, 64), 256, 0, stream>>>(Ob, WoT, B_ * LQ_, E_, E_, 2,
                                                 nullptr, nullptr, nullptr, nullptr, out, bo, gain);
}

// Round 5
// 348.745 us; speedup vs baseline: 1.1475x; 1.1475x over previous
//
#include <hip/hip_runtime.h>

#define B_ 4
#define LQ_ 2048
#define LK_ 2048
#define E_ 768
#define H_ 12
#define D_ 64
#define SCALE_ 0.03125f
// SCALE * log2(e) folded into Q projection so attention uses bare exp2
#define QSCALE_ 0.04508422f

using short8 = __attribute__((ext_vector_type(8))) short;
using f32x4  = __attribute__((ext_vector_type(4))) float;
using f32x16 = __attribute__((ext_vector_type(16))) float;

__device__ inline unsigned short f2bf(float f) {
    union { float f; unsigned u; } v; v.f = f;
    unsigned r = (v.u + 0x7FFFu + ((v.u >> 16) & 1u)) >> 16;
    return (unsigned short)r;
}

// pack two fp32 -> two bf16 in one u32 (round-half-up; P is softmax weight, 2% tol)
__device__ inline unsigned pkbf(float a, float b) {
    union { float f; unsigned u; } x, y; x.f = a; y.f = b;
    return ((x.u + 0x8000u) >> 16) | ((y.u + 0x8000u) & 0xffff0000u);
}

// async global->LDS, 16B per lane; LDS dest = uniform base + lane*16
__device__ inline void gll16(const void* g, void* l) {
    __builtin_amdgcn_global_load_lds(
        (const __attribute__((address_space(1))) unsigned int*)g,
        (__attribute__((address_space(3))) unsigned int*)l, 16, 0, 0);
}

// ---------------- LayerNorm: one wave per row of 768, fp32 -> bf16 ----------------
__global__ __launch_bounds__(256) void ln_kernel(
    const float* __restrict__ x, const float* __restrict__ g,
    const float* __restrict__ be, unsigned short* __restrict__ y, int rows)
{
    int wave = threadIdx.x >> 6, lane = threadIdx.x & 63;
    int row = blockIdx.x * 4 + wave;
    if (row >= rows) return;
    const float* xr = x + (size_t)row * E_;
    float4 v[3];
    float s = 0.f;
#pragma unroll
    for (int i = 0; i < 3; i++) {
        v[i] = *(const float4*)(xr + i * 256 + lane * 4);
        s += v[i].x + v[i].y + v[i].z + v[i].w;
    }
#pragma unroll
    for (int off = 32; off >= 1; off >>= 1) s += __shfl_xor(s, off);
    float mu = s * (1.0f / E_);
    float q = 0.f;
#pragma unroll
    for (int i = 0; i < 3; i++) {
        float dx = v[i].x - mu, dy = v[i].y - mu, dz = v[i].z - mu, dw = v[i].w - mu;
        q += dx * dx + dy * dy + dz * dz + dw * dw;
    }
#pragma unroll
    for (int off = 32; off >= 1; off >>= 1) q += __shfl_xor(q, off);
    float rstd = rsqrtf(q * (1.0f / E_) + 1e-5f);
    unsigned short* yr = y + (size_t)row * E_;
#pragma unroll
    for (int i = 0; i < 3; i++) {
        int c = i * 256 + lane * 4;
        float4 gv = *(const float4*)(g + c);
        float4 bv = *(const float4*)(be + c);
        ushort4 o;
        o.x = f2bf((v[i].x - mu) * rstd * gv.x + bv.x);
        o.y = f2bf((v[i].y - mu) * rstd * gv.y + bv.y);
        o.z = f2bf((v[i].z - mu) * rstd * gv.z + bv.z);
        o.w = f2bf((v[i].w - mu) * rstd * gv.w + bv.w);
        *(ushort4*)(yr + c) = o;
    }
}

// ---------------- transpose + cast: in f32 [R][C] -> out bf16 [C][R] ----------------
__global__ __launch_bounds__(256) void transpose_cast(
    const float* __restrict__ in, unsigned short* __restrict__ out, int R, int C)
{
    __shared__ float tile[32][33];
    int tx = threadIdx.x & 31, ty = threadIdx.x >> 5;
    int c0 = blockIdx.x * 32, r0 = blockIdx.y * 32;
#pragma unroll
    for (int i = 0; i < 32; i += 8)
        tile[ty + i][tx] = in[(size_t)(r0 + ty + i) * C + c0 + tx];
    __syncthreads();
#pragma unroll
    for (int i = 0; i < 32; i += 8)
        out[(size_t)(c0 + ty + i) * R + r0 + tx] = f2bf(tile[tx][ty + i]);
}

// ---------------- V transpose: Vb[bh][key][d] -> Vt[bh][d][key], bf16 ----------------
__global__ __launch_bounds__(256) void vtrans_kernel(
    const unsigned short* __restrict__ Vb, unsigned short* __restrict__ Vt)
{
    __shared__ unsigned short tile[64][72];
    int tid = threadIdx.x;
    int k0 = blockIdx.x * 64;
    size_t head = (size_t)blockIdx.y * LK_ * D_;
#pragma unroll
    for (int i = 0; i < 2; i++) {
        int row = (tid >> 3) + i * 32;
        int col = (tid & 7) * 8;
        *(short8*)(&tile[row][col]) = *(const short8*)(Vb + head + (size_t)(k0 + row) * D_ + col);
    }
    __syncthreads();
#pragma unroll
    for (int i = 0; i < 2; i++) {
        int d  = (tid >> 3) + i * 32;
        int kc = (tid & 7) * 8;
        short8 v;
#pragma unroll
        for (int j = 0; j < 8; j++) v[j] = (short)tile[kc + j][d];
        *(short8*)(Vt + head + (size_t)d * LK_ + k0 + kc) = v;
    }
}

// ---------------- GEMM: C[M][N] = A[M][K] * Bt[N][K]^T, bf16, gll + XOR swizzle ----
// LDS position p of row r holds data chunk p^(r&7) (16B chunks, 8 per 128B row).
#define BM 128
#define BN 128
#define BK 64
__global__ __launch_bounds__(256) void gemm_kernel(
    const unsigned short* __restrict__ A, const unsigned short* __restrict__ Bt,
    int M, int N, int K, int mode,
    unsigned short* __restrict__ outQ, const float* __restrict__ freqs,
    unsigned short* __restrict__ outK, unsigned short* __restrict__ outV,
    float* __restrict__ outF, const float* __restrict__ bo, const float* __restrict__ gain)
{
    __shared__ unsigned short Asm[BM][BK];
    __shared__ unsigned short Bsm[BN][BK];
    int tid = threadIdx.x;
    int wave = tid >> 6, lane = tid & 63;
    int quad = lane >> 4, l16 = lane & 15;
    int waveM = (wave >> 1) * 64, waveN = (wave & 1) * 64;
    int bn = blockIdx.x * BN, bm = blockIdx.y * BM;
    int ro = lane >> 3, cx = lane & 7;
    int sco = ((cx ^ ro) * 8);           // swizzled global chunk offset (elements)

    f32x4 acc[4][4] = {};

    for (int k0 = 0; k0 < K; k0 += BK) {
        const unsigned short* Ag = A + (size_t)(bm + wave * 32 + ro) * K + k0 + sco;
        const unsigned short* Bg = Bt + (size_t)(bn + wave * 32 + ro) * K + k0 + sco;
#pragma unroll
        for (int i = 0; i < 4; i++) {
            gll16(Ag + (size_t)(i * 8) * K, &Asm[wave * 32 + i * 8][0]);
            gll16(Bg + (size_t)(i * 8) * K, &Bsm[wave * 32 + i * 8][0]);
        }
        __syncthreads();
#pragma unroll
        for (int kk = 0; kk < BK; kk += 32) {
            short8 fa[4], fb[4];
#pragma unroll
            for (int t = 0; t < 4; t++) {
                int rA = waveM + t * 16 + l16;
                int rB = waveN + t * 16 + l16;
                int pos = ((quad + (kk >> 3)) ^ (l16 & 7)) * 8;   // chunk = quad + kk/8
                fa[t] = *(const short8*)(&Asm[rA][pos]);
                fb[t] = *(const short8*)(&Bsm[rB][pos]);
            }
#pragma unroll
            for (int mt = 0; mt < 4; mt++)
#pragma unroll
                for (int nt = 0; nt < 4; nt++)
                    acc[mt][nt] = __builtin_amdgcn_mfma_f32_16x16x32_bf16(fa[mt], fb[nt], acc[mt][nt], 0, 0, 0);
        }
        __syncthreads();
    }

    float gg = (mode == 2) ? gain[0] : 0.f;
#pragma unroll
    for (int mt = 0; mt < 4; mt++) {
#pragma unroll
        for (int nt = 0; nt < 4; nt++) {
#pragma unroll
            for (int r = 0; r < 4; r++) {
                int m = bm + waveM + mt * 16 + quad * 4 + r;
                int n = bn + waveN + nt * 16 + l16;
                float v = acc[mt][nt][r];
                if (mode == 2) {
                    outF[(size_t)m * E_ + n] = gg * (v + bo[n]);
                } else {
                    int l = m & (LQ_ - 1), bb = m >> 11;
                    float partner = __shfl_xor(v, 1);
                    if (mode == 1 && n >= E_) {
                        int nn = n - E_;
                        int h = nn >> 6, dd = nn & 63;
                        outV[(((size_t)bb * H_ + h) * LK_ + l) * D_ + dd] = f2bf(v);
                    } else {
                        int h = n >> 6, dd = n & 63;
                        const float* f = freqs + ((size_t)l * 32 + (dd >> 1)) * 2;
                        float f0 = f[0], f1 = f[1];
                        float o = ((dd & 1) == 0) ? (v * f0 - partner * f1)
                                                  : (partner * f1 + v * f0);
                        if (mode == 0) o *= QSCALE_;
                        unsigned short* dst = (mode == 0) ? outQ : outK;
                        dst[(((size_t)bb * H_ + h) * LQ_ + l) * D_ + dd] = f2bf(o);
                    }
                }
            }
        }
    }
}

// ---------------- flash attention: 32x32 MFMA, register P-transform, dbuf gll ------
// Q[B,H,LQ,64] (pre-scaled bf16), K[B,H,LK,64], Vt[B,H,64,LK] -> O[B*LQ][768] bf16
// LDS XOR swizzle as in gemm_kernel.
__global__ __launch_bounds__(256) void attn_kernel(
    const unsigned short* __restrict__ Qg, const unsigned short* __restrict__ Kg,
    const unsigned short* __restrict__ Vt, unsigned short* __restrict__ O)
{
    __shared__ unsigned short Ksm[2][64][64];   // [buf][key][d]   (chunk-swizzled)
    __shared__ unsigned short Vsm[2][64][64];   // [buf][d][key]   (chunk-swizzled)

    int tid = threadIdx.x;
    int wave = tid >> 6, lane = tid & 63;
    int l32 = lane & 31, hi = lane >> 5;
    int bh = blockIdx.y;
    int b = bh / H_, h = bh % H_;
    int qbase = blockIdx.x * 128 + wave * 32;

    const size_t head = (size_t)bh * LK_ * D_;
    const unsigned short* Qh = Qg + head;
    const unsigned short* Kh = Kg + head;
    const unsigned short* Vh = Vt + head;   // [d][key]

    // Q fragments: B-operand [k=d][n=q]: lane(n=l32,hi): d = dc*16 + hi*8 + j
    short8 qf[4];
#pragma unroll
    for (int dc = 0; dc < 4; dc++)
        qf[dc] = *(const short8*)(Qh + (size_t)(qbase + l32) * D_ + dc * 16 + hi * 8);

    f32x16 oacc[2] = {};
    float lsum = 0.f;

    int ro = lane >> 3, cx = lane & 7;
    int sco = ((cx ^ ro) * 8);           // swizzled global chunk offset (elements)
    int sw = l32 & 7;                    // read-side row swizzle key

    // stage tile 0 into buf 0
    {
        const unsigned short* Kp = Kh + (size_t)(wave * 16 + ro) * D_ + sco;
        const unsigned short* Vp = Vh + (size_t)(wave * 16 + ro) * LK_ + sco;
        gll16(Kp,            &Ksm[0][wave * 16][0]);
        gll16(Kp + 8 * D_,   &Ksm[0][wave * 16 + 8][0]);
        gll16(Vp,            &Vsm[0][wave * 16][0]);
        gll16(Vp + 8 * LK_,  &Vsm[0][wave * 16 + 8][0]);
    }
    asm volatile("s_waitcnt vmcnt(0)" ::: "memory");

    int buf = 0;
    for (int kt = 0; kt < LK_; kt += 64, buf ^= 1) {
        if (kt + 64 < LK_) {
            // prefetch next tile into other buffer; stays in flight across barrier.
            const unsigned short* Kp = Kh + (size_t)(kt + 64 + wave * 16 + ro) * D_ + sco;
            const unsigned short* Vp = Vh + (size_t)(wave * 16 + ro) * LK_ + kt + 64 + sco;
            gll16(Kp,           &Ksm[buf ^ 1][wave * 16][0]);
            gll16(Kp + 8 * D_,  &Ksm[buf ^ 1][wave * 16 + 8][0]);
            gll16(Vp,           &Vsm[buf ^ 1][wave * 16][0]);
            gll16(Vp + 8 * LK_, &Vsm[buf ^ 1][wave * 16 + 8][0]);
            // vmcnt(4): drain previous tile's 4 loads; our 4 prefetches stay in flight
            asm volatile("s_waitcnt vmcnt(4)\ns_barrier" ::: "memory");
        } else {
            asm volatile("s_waitcnt vmcnt(0)\ns_barrier" ::: "memory");
        }

#pragma unroll
        for (int half = 0; half < 2; half++) {
            // S^T[key][q]: A = K rows (M=key), B = Q (N=q), k-dim = d
            f32x16 st = {};
#pragma unroll
            for (int dc = 0; dc < 4; dc++) {
                int pos = ((dc * 2 + hi) ^ sw) * 8;     // data chunk dc*2+hi, swizzled
                short8 kfr = *(const short8*)(&Ksm[buf][half * 32 + l32][pos]);
                st = __builtin_amdgcn_mfma_f32_32x32x16_bf16(kfr, qf[dc], st, 0, 0, 0);
            }
            // exp2 + pack pairs (keys consecutive within reg pairs)
            unsigned pks[8];
#pragma unroll
            for (int t = 0; t < 8; t++) {
                float p0 = __builtin_amdgcn_exp2f(st[2 * t]);
                float p1 = __builtin_amdgcn_exp2f(st[2 * t + 1]);
                lsum += p0 + p1;
                pks[t] = pkbf(p0, p1);
            }
            unsigned y[8];
#pragma unroll
            for (int t = 0; t < 8; t++) y[t] = (unsigned)__shfl_xor((int)pks[t], 32);

            // PV: A = P[q][key] assembled in-register, B = Vt[d][key]
#pragma unroll
            for (int kk = 0; kk < 2; kk++) {
                union { unsigned u[4]; short8 s; } pf;
#pragma unroll
                for (int g = 0; g < 4; g++) {
                    int t0 = kk * 4 + (g & 1);
                    unsigned own = hi ? pks[t0 + 2] : pks[t0];
                    unsigned oth = hi ? y[t0 + 2]   : y[t0];
                    pf.u[g] = ((g >> 1) == hi) ? own : oth;
                }
#pragma unroll
                for (int dt = 0; dt < 2; dt++) {
                    int pos = (((half * 2 + kk) * 2 + hi) ^ sw) * 8;
                    short8 vfr = *(const short8*)(&Vsm[buf][dt * 32 + l32][pos]);
                    oacc[dt] = __builtin_amdgcn_mfma_f32_32x32x16_bf16(pf.s, vfr, oacc[dt], 0, 0, 0);
                }
            }
        }
        // WAR fence: all waves must finish reading buf before anyone prefetches
        // into it next iteration. Plain barrier — no vmcnt drain.
        asm volatile("s_waitcnt lgkmcnt(0)\ns_barrier" ::: "memory");
    }

    // epilogue: total row sums, normalize, store
    lsum += __shfl_xor(lsum, 32);          // lane(q,hi) + lane(q,hi^1): total for q=l32
    float inv = 1.f / lsum;
#pragma unroll
    for (int reg = 0; reg < 16; reg++) {
        int ql = (reg & 3) + 8 * (reg >> 2) + 4 * hi;   // wave-local q row of this reg
        float iq = __shfl(inv, ql);                      // lanes 0..31 hold q=lane
        int q = qbase + ql;
        size_t base = ((size_t)b * LQ_ + q) * E_ + h * D_;
#pragma unroll
        for (int dt = 0; dt < 2; dt++)
            O[base + dt * 32 + l32] = f2bf(oacc[dt][reg] * iq);
    }
}

extern "C" void kernel_launch(void* const* d_in, const int* in_sizes, int n_in,
                              void* d_out, int out_size, void* d_ws, size_t ws_size,
                              hipStream_t stream)
{
    const float* x_q     = (const float*)d_in[0];
    const float* x_kv    = (const float*)d_in[1];
    const float* freqs_q = (const float*)d_in[2];
    const float* freqs_k = (const float*)d_in[3];
    const float* Wq      = (const float*)d_in[4];
    const float* Wkv     = (const float*)d_in[5];
    const float* Wo      = (const float*)d_in[6];
    const float* bo      = (const float*)d_in[7];
    const float* ln_q_g  = (const float*)d_in[8];
    const float* ln_q_b  = (const float*)d_in[9];
    const float* ln_kv_g = (const float*)d_in[10];
    const float* ln_kv_b = (const float*)d_in[11];
    const float* gain    = (const float*)d_in[12];
    float* out = (float*)d_out;

    unsigned short* ws = (unsigned short*)d_ws;
    const size_t SZ = (size_t)B_ * LQ_ * E_;  // 6291456
    unsigned short* xq_ln  = ws;
    unsigned short* xkv_ln = xq_ln + SZ;
    unsigned short* Qb     = xkv_ln + SZ;
    unsigned short* Kb     = Qb + SZ;
    unsigned short* Vb     = Kb + SZ;
    unsigned short* Ob     = xq_ln;            // reuse (dead after Q GEMM)
    unsigned short* Vt     = xkv_ln;           // reuse (dead after KV GEMM)
    unsigned short* WqT    = Vb + SZ;
    unsigned short* WkvT   = WqT + E_ * E_;
    unsigned short* WoT    = WkvT + 2 * E_ * E_;

    ln_kernel<<<2048, 256, 0, stream>>>(x_q,  ln_q_g,  ln_q_b,  xq_ln,  B_ * LQ_);
    ln_kernel<<<2048, 256, 0, stream>>>(x_kv, ln_kv_g, ln_kv_b, xkv_ln, B_ * LK_);
    transpose_cast<<<dim3(24, 24), 256, 0, stream>>>(Wq,  WqT,  E_, E_);
    transpose_cast<<<dim3(48, 24), 256, 0, stream>>>(Wkv, WkvT, E_, 2 * E_);
    transpose_cast<<<dim3(24, 24), 256, 0, stream>>>(Wo,  WoT,  E_, E_);
    gemm_kernel<<<dim3(6, 64), 256, 0, stream>>>(xq_ln, WqT, B_ * LQ_, E_, E_, 0,
                                                 Qb, freqs_q, nullptr, nullptr, nullptr, nullptr, nullptr);
    gemm_kernel<<<dim3(12, 64), 256, 0, stream>>>(xkv_ln, WkvT, B_ * LK_, 2 * E_, E_, 1,
                                                  nullptr, freqs_k, Kb, Vb, nullptr, nullptr, nullptr);
    vtrans_kernel<<<dim3(32, 48), 256, 0, stream>>>(Vb, Vt);
    attn_kernel<<<dim3(16, 48), 256, 0, stream>>>(Qb, Kb, Vt, Ob);
    gemm_kernel<<<dim3(6, 64), 256, 0, stream>>>(Ob, WoT, B_ * LQ_, E_, E_, 2,
                                                 nullptr, nullptr, nullptr, nullptr, out, bo, gain);
}

// Round 6
// 287.415 us; speedup vs baseline: 1.3924x; 1.2134x over previous
//
#include <hip/hip_runtime.h>
#include <hip/hip_bf16.h>

#define B_ 4
#define LQ_ 2048
#define LK_ 2048
#define E_ 768
#define H_ 12
#define D_ 64
#define SCALE_ 0.03125f
// SCALE * log2(e) folded into Q projection so attention uses bare exp2
#define QSCALE_ 0.04508422f

using short8 = __attribute__((ext_vector_type(8))) short;
using f32x4  = __attribute__((ext_vector_type(4))) float;
using f32x16 = __attribute__((ext_vector_type(16))) float;

__device__ inline unsigned short f2bf(float f) {
    union { float f; unsigned u; } v; v.f = f;
    unsigned r = (v.u + 0x7FFFu + ((v.u >> 16) & 1u)) >> 16;
    return (unsigned short)r;
}

// pack two fp32 -> two bf16 in one u32 (round-half-up)
__device__ inline unsigned pkbf(float a, float b) {
    union { float f; unsigned u; } x, y; x.f = a; y.f = b;
    return ((x.u + 0x8000u) >> 16) | ((y.u + 0x8000u) & 0xffff0000u);
}

// packed HW convert (v_cvt_pk_bf16_f32 on gfx950)
__device__ inline unsigned pkcvt(float a, float b) {
    float2 p; p.x = a; p.y = b;
    __hip_bfloat162 pb = __float22bfloat162_rn(p);
    union { __hip_bfloat162 h; unsigned u; } c; c.h = pb;
    return c.u;
}

// async global->LDS, 16B per lane; LDS dest = uniform base + lane*16
__device__ inline void gll16(const void* g, void* l) {
    __builtin_amdgcn_global_load_lds(
        (const __attribute__((address_space(1))) unsigned int*)g,
        (__attribute__((address_space(3))) unsigned int*)l, 16, 0, 0);
}

// ---------------- LayerNorm (both inputs in one launch): wave per row, fp32->bf16 --
__global__ __launch_bounds__(256) void ln_kernel(
    const float* __restrict__ xq, const float* __restrict__ xkv,
    const float* __restrict__ gq, const float* __restrict__ bq,
    const float* __restrict__ gk, const float* __restrict__ bk,
    unsigned short* __restrict__ yq, unsigned short* __restrict__ ykv)
{
    int wave = threadIdx.x >> 6, lane = threadIdx.x & 63;
    int row = blockIdx.x * 4 + wave;          // 0..16383
    const float* x; const float* g; const float* be; unsigned short* y;
    if (row < 8192) { x = xq; g = gq; be = bq; y = yq; }
    else { row -= 8192; x = xkv; g = gk; be = bk; y = ykv; }
    const float* xr = x + (size_t)row * E_;
    float4 v[3];
    float s = 0.f;
#pragma unroll
    for (int i = 0; i < 3; i++) {
        v[i] = *(const float4*)(xr + i * 256 + lane * 4);
        s += v[i].x + v[i].y + v[i].z + v[i].w;
    }
#pragma unroll
    for (int off = 32; off >= 1; off >>= 1) s += __shfl_xor(s, off);
    float mu = s * (1.0f / E_);
    float q = 0.f;
#pragma unroll
    for (int i = 0; i < 3; i++) {
        float dx = v[i].x - mu, dy = v[i].y - mu, dz = v[i].z - mu, dw = v[i].w - mu;
        q += dx * dx + dy * dy + dz * dz + dw * dw;
    }
#pragma unroll
    for (int off = 32; off >= 1; off >>= 1) q += __shfl_xor(q, off);
    float rstd = rsqrtf(q * (1.0f / E_) + 1e-5f);
    unsigned short* yr = y + (size_t)row * E_;
#pragma unroll
    for (int i = 0; i < 3; i++) {
        int c = i * 256 + lane * 4;
        float4 gv = *(const float4*)(g + c);
        float4 bv = *(const float4*)(be + c);
        ushort4 o;
        o.x = f2bf((v[i].x - mu) * rstd * gv.x + bv.x);
        o.y = f2bf((v[i].y - mu) * rstd * gv.y + bv.y);
        o.z = f2bf((v[i].z - mu) * rstd * gv.z + bv.z);
        o.w = f2bf((v[i].w - mu) * rstd * gv.w + bv.w);
        *(ushort4*)(yr + c) = o;
    }
}

// ---------------- transpose + cast all 3 weights in one launch --------------------
__global__ __launch_bounds__(256) void transpose3_kernel(
    const float* __restrict__ Wq, const float* __restrict__ Wkv, const float* __restrict__ Wo,
    unsigned short* __restrict__ WqT, unsigned short* __restrict__ WkvT, unsigned short* __restrict__ WoT)
{
    __shared__ float tile[32][33];
    int z = blockIdx.z;
    const float* in; unsigned short* out; int C;
    if (z == 0)      { in = Wq;  out = WqT;  C = E_; }
    else if (z == 1) { in = Wkv; out = WkvT; C = 2 * E_; }
    else             { in = Wo;  out = WoT;  C = E_; }
    int c0 = blockIdx.x * 32, r0 = blockIdx.y * 32;
    if (c0 >= C) return;
    int tx = threadIdx.x & 31, ty = threadIdx.x >> 5;
#pragma unroll
    for (int i = 0; i < 32; i += 8)
        tile[ty + i][tx] = in[(size_t)(r0 + ty + i) * C + c0 + tx];
    __syncthreads();
#pragma unroll
    for (int i = 0; i < 32; i += 8)
        out[(size_t)(c0 + ty + i) * E_ + r0 + tx] = f2bf(tile[tx][ty + i]);
}

// ---------------- GEMM: C[M][N] = A[M][K] * Bt[N][K]^T, bf16, gll + XOR swizzle ----
// grid: (x = M/BMT m-tiles  [XCD-stationary A], y = N/128 n-tiles)
// mode 0: RoPE + QSCALE -> Q[B,H,L,64];  mode 1: K w/ RoPE, V transposed -> Vt;
// mode 2: gain*(v+bo) fp32.
#define BN 128
#define BK 64
template<int BMT>
__global__ __launch_bounds__(256) void gemm_kernel(
    const unsigned short* __restrict__ A, const unsigned short* __restrict__ Bt,
    int K, int mode,
    unsigned short* __restrict__ outQ, const float* __restrict__ freqs,
    unsigned short* __restrict__ outK, unsigned short* __restrict__ outV,
    float* __restrict__ outF, const float* __restrict__ bo, const float* __restrict__ gain)
{
    constexpr int MT = (BMT == 128) ? 4 : 2;             // 16-row m-tiles per wave
    constexpr int SMEMN = (BMT == 128) ? 128 * 136 : (BMT * 64 + 128 * 64);
    __shared__ __align__(16) unsigned short smem[SMEMN];
    auto Asm = (unsigned short (*)[BK])smem;             // [BMT][64]
    auto Bsm = (unsigned short (*)[BK])(smem + BMT * BK);// [128][64]

    int tid = threadIdx.x;
    int wave = tid >> 6, lane = tid & 63;
    int quad = lane >> 4, l16 = lane & 15;
    int waveM = (wave >> 1) * (MT * 16), waveN = (wave & 1) * 64;
    int bm = blockIdx.x * BMT, bn = blockIdx.y * BN;
    int ro = lane >> 3, cx = lane & 7;
    int sco = ((cx ^ ro) * 8);           // swizzled global chunk offset (elements)

    f32x4 acc[MT][4] = {};

    for (int k0 = 0; k0 < K; k0 += BK) {
        const unsigned short* Ag = A + (size_t)(bm + wave * (BMT / 4) + ro) * K + k0 + sco;
        const unsigned short* Bg = Bt + (size_t)(bn + wave * 32 + ro) * K + k0 + sco;
#pragma unroll
        for (int i = 0; i < BMT / 32; i++)
            gll16(Ag + (size_t)(i * 8) * K, &Asm[wave * (BMT / 4) + i * 8][0]);
#pragma unroll
        for (int i = 0; i < 4; i++)
            gll16(Bg + (size_t)(i * 8) * K, &Bsm[wave * 32 + i * 8][0]);
        __syncthreads();
#pragma unroll
        for (int kk = 0; kk < BK; kk += 32) {
            short8 fa[MT], fb[4];
#pragma unroll
            for (int t = 0; t < 4; t++) {
                int pos = ((quad + (kk >> 3)) ^ (l16 & 7)) * 8;
                if (t < MT) fa[t] = *(const short8*)(&Asm[waveM + t * 16 + l16][pos]);
                fb[t] = *(const short8*)(&Bsm[waveN + t * 16 + l16][pos]);
            }
#pragma unroll
            for (int mt = 0; mt < MT; mt++)
#pragma unroll
                for (int nt = 0; nt < 4; nt++)
                    acc[mt][nt] = __builtin_amdgcn_mfma_f32_16x16x32_bf16(fa[mt], fb[nt], acc[mt][nt], 0, 0, 0);
        }
        __syncthreads();
    }

    if (BMT == 128 && mode == 1 && bn >= E_) {
        // ---- V block: transposed store via LDS bounce -> Vt[bh][d][key] ----
        auto T = (unsigned short (*)[136])smem;
#pragma unroll
        for (int mt = 0; mt < MT; mt++) {
#pragma unroll
            for (int nt = 0; nt < 4; nt++) {
                int ml = waveM + mt * 16 + quad * 4;
                int nl = waveN + nt * 16 + l16;
                *(unsigned*)&T[nl][ml]     = pkbf(acc[mt][nt][0], acc[mt][nt][1]);
                *(unsigned*)&T[nl][ml + 2] = pkbf(acc[mt][nt][2], acc[mt][nt][3]);
            }
        }
        __syncthreads();
        int nnbase = bn - E_;
        int bb = bm >> 11, l0 = bm & (LQ_ - 1);
#pragma unroll
        for (int it = 0; it < 8; it++) {
            int row = it * 16 + (tid >> 4);
            int hh = (nnbase + row) >> 6, dd = (nnbase + row) & 63;
            short8 v = *(const short8*)&T[row][(tid & 15) * 8];
            *(short8*)(outV + (((size_t)bb * H_ + hh) * D_ + dd) * LK_ + l0 + (tid & 15) * 8) = v;
        }
        return;
    }

    float gg = (mode == 2) ? gain[0] : 0.f;
#pragma unroll
    for (int mt = 0; mt < MT; mt++) {
#pragma unroll
        for (int nt = 0; nt < 4; nt++) {
#pragma unroll
            for (int r = 0; r < 4; r++) {
                int m = bm + waveM + mt * 16 + quad * 4 + r;
                int n = bn + waveN + nt * 16 + l16;
                float v = acc[mt][nt][r];
                if (mode == 2) {
                    outF[(size_t)m * E_ + n] = gg * (v + bo[n]);
                } else {
                    int l = m & (LQ_ - 1), bb = m >> 11;
                    float partner = __shfl_xor(v, 1);
                    int h = n >> 6, dd = n & 63;
                    const float* f = freqs + ((size_t)l * 32 + (dd >> 1)) * 2;
                    float f0 = f[0], f1 = f[1];
                    float o = ((dd & 1) == 0) ? (v * f0 - partner * f1)
                                              : (partner * f1 + v * f0);
                    if (mode == 0) o *= QSCALE_;
                    unsigned short* dst = (mode == 0) ? outQ : outK;
                    dst[(((size_t)bb * H_ + h) * LQ_ + l) * D_ + dd] = f2bf(o);
                }
            }
        }
    }
}

// ---------------- flash attention: 32x32 MFMA, register P-transform, dbuf gll ------
// grid: (x = bh  [XCD-stationary K/V], y = q-block)
__global__ __launch_bounds__(256) void attn_kernel(
    const unsigned short* __restrict__ Qg, const unsigned short* __restrict__ Kg,
    const unsigned short* __restrict__ Vt, unsigned short* __restrict__ O)
{
    __shared__ unsigned short Ksm[2][64][64];   // [buf][key][d]   (chunk-swizzled)
    __shared__ unsigned short Vsm[2][64][64];   // [buf][d][key]   (chunk-swizzled)

    int tid = threadIdx.x;
    int wave = tid >> 6, lane = tid & 63;
    int l32 = lane & 31, hi = lane >> 5;
    int bh = blockIdx.x;
    int b = bh / H_, h = bh % H_;
    int qbase = blockIdx.y * 128 + wave * 32;

    const size_t head = (size_t)bh * LK_ * D_;
    const unsigned short* Qh = Qg + head;
    const unsigned short* Kh = Kg + head;
    const unsigned short* Vh = Vt + head;   // [d][key]

    // Q fragments: B-operand [k=d][n=q]: lane(n=l32,hi): d = dc*16 + hi*8 + j
    short8 qf[4];
#pragma unroll
    for (int dc = 0; dc < 4; dc++)
        qf[dc] = *(const short8*)(Qh + (size_t)(qbase + l32) * D_ + dc * 16 + hi * 8);

    f32x16 oacc[2] = {};
    float lsum = 0.f;

    int ro = lane >> 3, cx = lane & 7;
    int sco = ((cx ^ ro) * 8);
    int sw = l32 & 7;

    // stage tile 0 into buf 0
    {
        const unsigned short* Kp = Kh + (size_t)(wave * 16 + ro) * D_ + sco;
        const unsigned short* Vp = Vh + (size_t)(wave * 16 + ro) * LK_ + sco;
        gll16(Kp,            &Ksm[0][wave * 16][0]);
        gll16(Kp + 8 * D_,   &Ksm[0][wave * 16 + 8][0]);
        gll16(Vp,            &Vsm[0][wave * 16][0]);
        gll16(Vp + 8 * LK_,  &Vsm[0][wave * 16 + 8][0]);
    }
    asm volatile("s_waitcnt vmcnt(0)" ::: "memory");

    int buf = 0;
    for (int kt = 0; kt < LK_; kt += 64, buf ^= 1) {
        if (kt + 64 < LK_) {
            const unsigned short* Kp = Kh + (size_t)(kt + 64 + wave * 16 + ro) * D_ + sco;
            const unsigned short* Vp = Vh + (size_t)(wave * 16 + ro) * LK_ + kt + 64 + sco;
            gll16(Kp,           &Ksm[buf ^ 1][wave * 16][0]);
            gll16(Kp + 8 * D_,  &Ksm[buf ^ 1][wave * 16 + 8][0]);
            gll16(Vp,           &Vsm[buf ^ 1][wave * 16][0]);
            gll16(Vp + 8 * LK_, &Vsm[buf ^ 1][wave * 16 + 8][0]);
            asm volatile("s_waitcnt vmcnt(4)\ns_barrier" ::: "memory");
        } else {
            asm volatile("s_waitcnt vmcnt(0)\ns_barrier" ::: "memory");
        }

#pragma unroll
        for (int half = 0; half < 2; half++) {
            // S^T[key][q]: A = K rows (M=key), B = Q (N=q), k-dim = d
            f32x16 st = {};
#pragma unroll
            for (int dc = 0; dc < 4; dc++) {
                int pos = ((dc * 2 + hi) ^ sw) * 8;
                short8 kfr = *(const short8*)(&Ksm[buf][half * 32 + l32][pos]);
                st = __builtin_amdgcn_mfma_f32_32x32x16_bf16(kfr, qf[dc], st, 0, 0, 0);
            }
            // exp2 + packed HW bf16 convert
            unsigned pks[8];
#pragma unroll
            for (int t = 0; t < 8; t++) {
                float p0 = __builtin_amdgcn_exp2f(st[2 * t]);
                float p1 = __builtin_amdgcn_exp2f(st[2 * t + 1]);
                lsum += p0 + p1;
                pks[t] = pkcvt(p0, p1);
            }
            unsigned y[8];
#pragma unroll
            for (int t = 0; t < 8; t++) y[t] = (unsigned)__shfl_xor((int)pks[t], 32);

            // PV: A = P[q][key] assembled in-register, B = Vt[d][key]
#pragma unroll
            for (int kk = 0; kk < 2; kk++) {
                union { unsigned u[4]; short8 s; } pf;
#pragma unroll
                for (int g = 0; g < 4; g++) {
                    int t0 = kk * 4 + (g & 1);
                    unsigned own = hi ? pks[t0 + 2] : pks[t0];
                    unsigned oth = hi ? y[t0 + 2]   : y[t0];
                    pf.u[g] = ((g >> 1) == hi) ? own : oth;
                }
#pragma unroll
                for (int dt = 0; dt < 2; dt++) {
                    int pos = (((half * 2 + kk) * 2 + hi) ^ sw) * 8;
                    short8 vfr = *(const short8*)(&Vsm[buf][dt * 32 + l32][pos]);
                    oacc[dt] = __builtin_amdgcn_mfma_f32_32x32x16_bf16(pf.s, vfr, oacc[dt], 0, 0, 0);
                }
            }
        }
        // WAR fence: no vmcnt drain — prefetch stays in flight.
        asm volatile("s_waitcnt lgkmcnt(0)\ns_barrier" ::: "memory");
    }

    // epilogue: total row sums, normalize, store
    lsum += __shfl_xor(lsum, 32);
    float inv = 1.f / lsum;
#pragma unroll
    for (int reg = 0; reg < 16; reg++) {
        int ql = (reg & 3) + 8 * (reg >> 2) + 4 * hi;
        float iq = __shfl(inv, ql);
        int q = qbase + ql;
        size_t base = ((size_t)b * LQ_ + q) * E_ + h * D_;
#pragma unroll
        for (int dt = 0; dt < 2; dt++)
            O[base + dt * 32 + l32] = f2bf(oacc[dt][reg] * iq);
    }
}

extern "C" void kernel_launch(void* const* d_in, const int* in_sizes, int n_in,
                              void* d_out, int out_size, void* d_ws, size_t ws_size,
                              hipStream_t stream)
{
    const float* x_q     = (const float*)d_in[0];
    const float* x_kv    = (const float*)d_in[1];
    const float* freqs_q = (const float*)d_in[2];
    const float* freqs_k = (const float*)d_in[3];
    const float* Wq      = (const float*)d_in[4];
    const float* Wkv     = (const float*)d_in[5];
    const float* Wo      = (const float*)d_in[6];
    const float* bo      = (const float*)d_in[7];
    const float* ln_q_g  = (const float*)d_in[8];
    const float* ln_q_b  = (const float*)d_in[9];
    const float* ln_kv_g = (const float*)d_in[10];
    const float* ln_kv_b = (const float*)d_in[11];
    const float* gain    = (const float*)d_in[12];
    float* out = (float*)d_out;

    unsigned short* ws = (unsigned short*)d_ws;
    const size_t SZ = (size_t)B_ * LQ_ * E_;  // 6291456
    unsigned short* xq_ln  = ws;
    unsigned short* xkv_ln = xq_ln + SZ;
    unsigned short* Qb     = xkv_ln + SZ;
    unsigned short* Kb     = Qb + SZ;
    unsigned short* Vt     = Kb + SZ;          // filled transposed by KV-GEMM
    unsigned short* Ob     = xq_ln;            // reuse (dead after Q GEMM)
    unsigned short* WqT    = Vt + SZ;
    unsigned short* WkvT   = WqT + E_ * E_;
    unsigned short* WoT    = WkvT + 2 * E_ * E_;

    ln_kernel<<<4096, 256, 0, stream>>>(x_q, x_kv, ln_q_g, ln_q_b, ln_kv_g, ln_kv_b,
                                        xq_ln, xkv_ln);
    transpose3_kernel<<<dim3(48, 24, 3), 256, 0, stream>>>(Wq, Wkv, Wo, WqT, WkvT, WoT);
    gemm_kernel<64><<<dim3(128, 6), 256, 0, stream>>>(xq_ln, WqT, E_, 0,
                                                      Qb, freqs_q, nullptr, nullptr, nullptr, nullptr, nullptr);
    gemm_kernel<128><<<dim3(64, 12), 256, 0, stream>>>(xkv_ln, WkvT, E_, 1,
                                                       nullptr, freqs_k, Kb, Vt, nullptr, nullptr, nullptr);
    attn_kernel<<<dim3(48, 16), 256, 0, stream>>>(Qb, Kb, Vt, Ob);
    gemm_kernel<64><<<dim3(128, 6), 256, 0, stream>>>(Ob, WoT, E_, 2,
                                                      nullptr, nullptr, nullptr, nullptr, out, bo, gain);
}